// Round 1
// baseline (2314.588 us; speedup 1.0000x reference)
//
#include <hip/hip_runtime.h>

// GCN forward: 2-layer GCN (shared across both branches since dropout is
// identity in eval mode => x1 == x2), fused concat-linear, log_softmax.
//
// Dims (fixed by the reference): N=50000, E=800000, CIN=128, CHID=128, COUT=64.
// Derived at launch from in_sizes for robustness.

#define CIN  128
#define CHID 128
#define COUT 64

// ---------------- degree ----------------
__global__ void deg_count_kernel(const int* __restrict__ dst, int* __restrict__ cnt, int E) {
    int e = blockIdx.x * blockDim.x + threadIdx.x;
    if (e < E) atomicAdd(&cnt[dst[e]], 1);
}

__global__ void inv_sqrt_kernel(const int* __restrict__ cnt, float* __restrict__ inv, int n) {
    int i = blockIdx.x * blockDim.x + threadIdx.x;
    if (i < n) inv[i] = rsqrtf((float)(cnt[i] + 1));  // +1 for the always-added self-loop
}

// ---------------- dense GEMM: one node-row per block ----------------
// H[node, j] = sum_k X[node, k] * W[k, j].  blockDim = N_OUT threads.
template <int K, int NOUT>
__global__ void gemm_rowblock(const float* __restrict__ X, const float* __restrict__ W,
                              float* __restrict__ H, int n) {
    __shared__ float xs[K];
    int node = blockIdx.x;
    if (node >= n) return;
    int j = threadIdx.x;
    for (int k = j; k < K; k += NOUT) xs[k] = X[(size_t)node * K + k];
    __syncthreads();
    float acc = 0.f;
#pragma unroll 8
    for (int k = 0; k < K; ++k) acc = fmaf(xs[k], W[k * NOUT + j], acc);
    H[(size_t)node * NOUT + j] = acc;
}

// ---------------- edge scatter: out[dst] += coeff * h[src] ----------------
// TPE threads per edge, each thread handles 4 channels (float4 gather, 4 atomics).
template <int C>
__global__ void scatter_kernel(const float* __restrict__ h, const int* __restrict__ src,
                               const int* __restrict__ dst, const float* __restrict__ inv,
                               float* __restrict__ out, int E) {
    constexpr int TPE = C / 4;
    int t = blockIdx.x * blockDim.x + threadIdx.x;
    int e = t / TPE;
    int lane = t % TPE;
    if (e >= E) return;
    int s = src[e];
    int d = dst[e];
    float c = inv[s] * inv[d];
    float4 v = ((const float4*)(h + (size_t)s * C))[lane];
    float* op = out + (size_t)d * C + lane * 4;
    atomicAdd(op + 0, c * v.x);
    atomicAdd(op + 1, c * v.y);
    atomicAdd(op + 2, c * v.z);
    atomicAdd(op + 3, c * v.w);
}

// ---------------- epilogue: acc += inv[i]^2 * h[i] (self-loop) + bias; optional relu ----------
template <int C, bool RELU>
__global__ void finish_kernel(float* __restrict__ acc, const float* __restrict__ h,
                              const float* __restrict__ inv, const float* __restrict__ bias,
                              int n) {
    int t = blockIdx.x * blockDim.x + threadIdx.x;  // over n*C/4 float4s
    int total = n * (C / 4);
    if (t >= total) return;
    int i  = t / (C / 4);
    int j4 = (t % (C / 4)) * 4;
    float ic = inv[i];
    ic = ic * ic;
    float4 a  = ((float4*)acc)[t];
    float4 hv = ((const float4*)h)[t];
    a.x = fmaf(ic, hv.x, a.x) + bias[j4 + 0];
    a.y = fmaf(ic, hv.y, a.y) + bias[j4 + 1];
    a.z = fmaf(ic, hv.z, a.z) + bias[j4 + 2];
    a.w = fmaf(ic, hv.w, a.w) + bias[j4 + 3];
    if (RELU) {
        a.x = fmaxf(a.x, 0.f); a.y = fmaxf(a.y, 0.f);
        a.z = fmaxf(a.z, 0.f); a.w = fmaxf(a.w, 0.f);
    }
    ((float4*)acc)[t] = a;
}

// ---------------- final: y = log_softmax(z @ (linW_top + linW_bot) + linb) ----------------
// One node per block, 64 threads = 1 wave. Wave-wide shuffle reductions.
__global__ void final_kernel(const float* __restrict__ z, const float* __restrict__ linW,
                             const float* __restrict__ linb, float* __restrict__ y, int n) {
    int node = blockIdx.x;
    if (node >= n) return;
    int j = threadIdx.x;  // 0..63
    __shared__ float row[COUT];
    row[j] = z[(size_t)node * COUT + j];
    __syncthreads();
    float acc = linb[j];
#pragma unroll 8
    for (int k = 0; k < COUT; ++k)
        acc = fmaf(row[k], linW[k * COUT + j] + linW[(k + COUT) * COUT + j], acc);
    // log_softmax across the 64 lanes (exactly one wave)
    float m = acc;
#pragma unroll
    for (int off = 32; off >= 1; off >>= 1) m = fmaxf(m, __shfl_xor(m, off, 64));
    float ex = expf(acc - m);
    float s = ex;
#pragma unroll
    for (int off = 32; off >= 1; off >>= 1) s += __shfl_xor(s, off, 64);
    y[(size_t)node * COUT + j] = acc - m - logf(s);
}

extern "C" void kernel_launch(void* const* d_in, const int* in_sizes, int n_in,
                              void* d_out, int out_size, void* d_ws, size_t ws_size,
                              hipStream_t stream) {
    const float* x     = (const float*)d_in[0];
    const int*   eidx  = (const int*)d_in[1];   // [2, E] int (src row then dst row)
    const float* W1    = (const float*)d_in[2];
    const float* b1    = (const float*)d_in[3];
    const float* W2    = (const float*)d_in[4];
    const float* b2    = (const float*)d_in[5];
    const float* linW  = (const float*)d_in[6];
    const float* linb  = (const float*)d_in[7];
    float* out = (float*)d_out;

    const int n = in_sizes[0] / CIN;      // 50000
    const int E = in_sizes[1] / 2;        // 800000
    const int* src = eidx;
    const int* dst = eidx + E;

    // ---- workspace layout (floats), ws re-poisoned each call => must memset what needs zeros
    char* ws = (char*)d_ws;
    int*   cnt  = (int*)ws;                                   // n ints
    float* inv  = (float*)(ws + (size_t)n * 4);               // n floats
    float* h1   = (float*)(ws + (size_t)n * 8);               // n*128
    float* agg1 = h1 + (size_t)n * CHID;                      // n*128
    float* h2   = agg1 + (size_t)n * CHID;                    // n*64
    float* agg2 = h1;                                         // alias: h1 dead after finish<128,relu>

    // ---- zero what needs zeroing
    hipMemsetAsync(cnt, 0, (size_t)n * 4, stream);
    hipMemsetAsync(agg1, 0, (size_t)n * CHID * 4, stream);

    // ---- degree + normalization
    deg_count_kernel<<<(E + 255) / 256, 256, 0, stream>>>(dst, cnt, E);
    inv_sqrt_kernel<<<(n + 255) / 256, 256, 0, stream>>>(cnt, inv, n);

    // ---- layer 1: h1 = x @ W1 ; agg1 = scatter + self + b1, relu
    gemm_rowblock<CIN, CHID><<<n, CHID, 0, stream>>>(x, W1, h1, n);
    {
        const int TPE = CHID / 4;  // 32 threads/edge
        long long threads = (long long)E * TPE;
        scatter_kernel<CHID><<<(int)((threads + 255) / 256), 256, 0, stream>>>(h1, src, dst, inv, agg1, E);
    }
    finish_kernel<CHID, true><<<(n * (CHID / 4) + 255) / 256, 256, 0, stream>>>(agg1, h1, inv, b1, n);

    // h1 is now dead -> reuse its space for agg2 (zero it first)
    hipMemsetAsync(agg2, 0, (size_t)n * COUT * 4, stream);

    // ---- layer 2: h2 = agg1 @ W2 ; agg2 = scatter + self + b2
    gemm_rowblock<CHID, COUT><<<n, COUT, 0, stream>>>(agg1, W2, h2, n);
    {
        const int TPE = COUT / 4;  // 16 threads/edge
        long long threads = (long long)E * TPE;
        scatter_kernel<COUT><<<(int)((threads + 255) / 256), 256, 0, stream>>>(h2, src, dst, inv, agg2, E);
    }
    finish_kernel<COUT, false><<<(n * (COUT / 4) + 255) / 256, 256, 0, stream>>>(agg2, h2, inv, b2, n);

    // ---- fused concat-linear + log_softmax (x1 == x2 => single branch, summed weight halves)
    final_kernel<<<n, COUT, 0, stream>>>(agg2, linW, linb, out, n);
}

// Round 2
// 494.504 us; speedup vs baseline: 4.6806x; 4.6806x over previous
//
#include <hip/hip_runtime.h>

// GCN forward, CSR-gather formulation (no feature atomics).
// x1 == x2 (dropout = identity) => one branch + summed lin_W halves.
// out[i] = inv[i] * sum_{e: dst=i} inv[src] * h[src]  +  inv[i]^2 * h[i] + b
// (inv[dst] factored out of the edge loop).

#define CIN  128
#define CHID 128
#define COUT 64
#define SCAN_T 1024

// ---------------- degree ----------------
__global__ void deg_count_kernel(const int* __restrict__ dst, int* __restrict__ cnt, int E) {
    int e = blockIdx.x * blockDim.x + threadIdx.x;
    if (e < E) atomicAdd(&cnt[dst[e]], 1);
}

__global__ void inv_sqrt_kernel(const int* __restrict__ cnt, float* __restrict__ inv, int n) {
    int i = blockIdx.x * blockDim.x + threadIdx.x;
    if (i < n) inv[i] = rsqrtf((float)(cnt[i] + 1));  // +1: self-loop
}

// ---------------- single-block exclusive scan over n counts ----------------
__global__ __launch_bounds__(SCAN_T) void scan_kernel(const int* __restrict__ cnt,
                                                      int* __restrict__ rowptr,
                                                      int* __restrict__ cursor,
                                                      int n, int E) {
    __shared__ int sums[SCAN_T];
    int t = threadIdx.x;
    int chunk = (n + SCAN_T - 1) / SCAN_T;
    int b = t * chunk;
    int e = b + chunk; if (e > n) e = n;
    int p = 0;
    for (int i = b; i < e; ++i) p += cnt[i];
    sums[t] = p;
    __syncthreads();
    for (int off = 1; off < SCAN_T; off <<= 1) {   // Hillis-Steele inclusive
        int v = (t >= off) ? sums[t - off] : 0;
        __syncthreads();
        sums[t] += v;
        __syncthreads();
    }
    int run = sums[t] - p;                          // exclusive prefix of this chunk
    for (int i = b; i < e; ++i) {
        rowptr[i] = run; cursor[i] = run; run += cnt[i];
    }
    if (t == 0) rowptr[n] = E;
}

// ---------------- bucket-fill: ebuf[rowptr[dst]..] = src ids ----------------
__global__ void fill_kernel(const int* __restrict__ src, const int* __restrict__ dst,
                            int* __restrict__ cursor, int* __restrict__ ebuf, int E) {
    int e = blockIdx.x * blockDim.x + threadIdx.x;
    if (e >= E) return;
    int pos = atomicAdd(&cursor[dst[e]], 1);
    ebuf[pos] = src[e];
}

// ---------------- register-blocked row GEMM: H = X @ W ----------------
// NOUT threads; R rows per block; xs reads are wave-uniform broadcasts (conflict-free).
template <int K, int NOUT, int R>
__global__ void gemm_rows(const float* __restrict__ X, const float* __restrict__ W,
                          float* __restrict__ H, int n) {
    __shared__ float xs[R][K];
    int j = threadIdx.x;
    int n0 = blockIdx.x * R;
#pragma unroll
    for (int r = 0; r < R; ++r)
        for (int k = j; k < K; k += NOUT)
            xs[r][k] = (n0 + r < n) ? X[(size_t)(n0 + r) * K + k] : 0.f;
    __syncthreads();
    float acc[R];
#pragma unroll
    for (int r = 0; r < R; ++r) acc[r] = 0.f;
#pragma unroll 4
    for (int k = 0; k < K; ++k) {
        float wv = W[k * NOUT + j];
#pragma unroll
        for (int r = 0; r < R; ++r) acc[r] = fmaf(xs[r][k], wv, acc[r]);
    }
#pragma unroll
    for (int r = 0; r < R; ++r)
        if (n0 + r < n) H[(size_t)(n0 + r) * NOUT + j] = acc[r];
}

// ---------------- layer-1 aggregate (C=128): wave per node, float2 per lane ------
// agg[i] = relu( inv[i]*sum inv[s]*h[s] + inv[i]^2*h[i] + b )
__global__ void agg1_kernel(const float* __restrict__ h, const int* __restrict__ ebuf,
                            const int* __restrict__ rowptr, const float* __restrict__ inv,
                            const float* __restrict__ bias, float* __restrict__ outp, int n) {
    int node = blockIdx.x * 4 + (threadIdx.x >> 6);
    int lane = threadIdx.x & 63;
    if (node >= n) return;
    int beg = rowptr[node], end = rowptr[node + 1];
    const float2* H = (const float2*)h;
    float2 acc = make_float2(0.f, 0.f);
    for (int base = beg; base < end; base += 64) {
        int m = end - base; if (m > 64) m = 64;
        int sid = 0; float sv = 0.f;
        if (lane < m) { sid = ebuf[base + lane]; sv = inv[sid]; }
        for (int k = 0; k < m; ++k) {
            int s   = __shfl(sid, k, 64);
            float w = __shfl(sv, k, 64);
            float2 hv = H[(size_t)s * 64 + lane];
            acc.x = fmaf(w, hv.x, acc.x);
            acc.y = fmaf(w, hv.y, acc.y);
        }
    }
    float wd = inv[node];
    float2 hd = H[(size_t)node * 64 + lane];
    float2 bv = ((const float2*)bias)[lane];
    float ox = fmaf(wd, acc.x, wd * wd * hd.x) + bv.x;
    float oy = fmaf(wd, acc.y, wd * wd * hd.y) + bv.y;
    ox = fmaxf(ox, 0.f); oy = fmaxf(oy, 0.f);
    ((float2*)outp)[(size_t)node * 64 + lane] = make_float2(ox, oy);
}

// ---------------- Wsum = linW[0:64,:] + linW[64:128,:] ----------------
__global__ void wsum_kernel(const float* __restrict__ linW, float* __restrict__ Wsum) {
    int i = blockIdx.x * blockDim.x + threadIdx.x;
    if (i < COUT * COUT) Wsum[i] = linW[i] + linW[COUT * COUT + i];
}

// ---------------- layer-2 aggregate + fused concat-linear + log_softmax --------
// wave per node; lane owns channel `lane` of z (C=64).
__global__ void agg2_final_kernel(const float* __restrict__ h, const int* __restrict__ ebuf,
                                  const int* __restrict__ rowptr, const float* __restrict__ inv,
                                  const float* __restrict__ bias, const float* __restrict__ Wsum,
                                  const float* __restrict__ linb, float* __restrict__ outp, int n) {
    int node = blockIdx.x * 4 + (threadIdx.x >> 6);
    int lane = threadIdx.x & 63;
    if (node >= n) return;
    int beg = rowptr[node], end = rowptr[node + 1];
    float acc = 0.f;
    for (int base = beg; base < end; base += 64) {
        int m = end - base; if (m > 64) m = 64;
        int sid = 0; float sv = 0.f;
        if (lane < m) { sid = ebuf[base + lane]; sv = inv[sid]; }
        for (int k = 0; k < m; ++k) {
            int s   = __shfl(sid, k, 64);
            float w = __shfl(sv, k, 64);
            acc = fmaf(w, h[(size_t)s * 64 + lane], acc);
        }
    }
    float wd = inv[node];
    float z = fmaf(wd, acc, wd * wd * h[(size_t)node * 64 + lane]) + bias[lane];
    // fused (concat @ linW + linb): fo_j = linb_j + sum_k z_k * Wsum[k][j]
    float fo = linb[lane];
#pragma unroll 8
    for (int k = 0; k < COUT; ++k) {
        float zk = __shfl(z, k, 64);
        fo = fmaf(zk, Wsum[k * COUT + lane], fo);
    }
    // log_softmax across 64 lanes (one wave)
    float mx = fo;
#pragma unroll
    for (int off = 32; off >= 1; off >>= 1) mx = fmaxf(mx, __shfl_xor(mx, off, 64));
    float ex = expf(fo - mx);
    float s = ex;
#pragma unroll
    for (int off = 32; off >= 1; off >>= 1) s += __shfl_xor(s, off, 64);
    outp[(size_t)node * COUT + lane] = fo - mx - logf(s);
}

static inline size_t align16(size_t x) { return (x + 15) & ~(size_t)15; }

extern "C" void kernel_launch(void* const* d_in, const int* in_sizes, int n_in,
                              void* d_out, int out_size, void* d_ws, size_t ws_size,
                              hipStream_t stream) {
    const float* x    = (const float*)d_in[0];
    const int*   eidx = (const int*)d_in[1];
    const float* W1   = (const float*)d_in[2];
    const float* b1   = (const float*)d_in[3];
    const float* W2   = (const float*)d_in[4];
    const float* b2   = (const float*)d_in[5];
    const float* linW = (const float*)d_in[6];
    const float* linb = (const float*)d_in[7];
    float* out = (float*)d_out;

    const int n = in_sizes[0] / CIN;   // 50000
    const int E = in_sizes[1] / 2;     // 800000
    const int* src = eidx;
    const int* dst = eidx + E;

    // ---- workspace carve-up
    char* ws = (char*)d_ws;
    size_t off = 0;
    int*   cnt    = (int*)(ws + off);  off = align16(off + (size_t)n * 4);
    int*   rowptr = (int*)(ws + off);  off = align16(off + (size_t)(n + 1) * 4);
    int*   cursor = (int*)(ws + off);  off = align16(off + (size_t)n * 4);
    float* inv    = (float*)(ws + off); off = align16(off + (size_t)n * 4);
    float* Wsum   = (float*)(ws + off); off = align16(off + (size_t)COUT * COUT * 4);
    int*   ebuf   = (int*)(ws + off);  off = align16(off + (size_t)E * 4);
    float* bufA   = (float*)(ws + off); off = align16(off + (size_t)n * CHID * 4); // h1 then h2
    float* bufB   = (float*)(ws + off); off = align16(off + (size_t)n * CHID * 4); // agg1

    hipMemsetAsync(cnt, 0, (size_t)n * 4, stream);

    // ---- CSR build
    deg_count_kernel<<<(E + 255) / 256, 256, 0, stream>>>(dst, cnt, E);
    scan_kernel<<<1, SCAN_T, 0, stream>>>(cnt, rowptr, cursor, n, E);
    inv_sqrt_kernel<<<(n + 255) / 256, 256, 0, stream>>>(cnt, inv, n);
    fill_kernel<<<(E + 255) / 256, 256, 0, stream>>>(src, dst, cursor, ebuf, E);
    wsum_kernel<<<(COUT * COUT + 255) / 256, 256, 0, stream>>>(linW, Wsum);

    // ---- layer 1: h1 = x @ W1 ; agg1 = gather + self + b1, relu
    gemm_rows<CIN, CHID, 4><<<(n + 3) / 4, CHID, 0, stream>>>(x, W1, bufA, n);
    agg1_kernel<<<(n + 3) / 4, 256, 0, stream>>>(bufA, ebuf, rowptr, inv, b1, bufB, n);

    // ---- layer 2: h2 = agg1 @ W2 (into bufA; h1 dead) ; fused agg+final
    gemm_rows<CHID, COUT, 8><<<(n + 7) / 8, COUT, 0, stream>>>(bufB, W2, bufA, n);
    agg2_final_kernel<<<(n + 3) / 4, 256, 0, stream>>>(bufA, ebuf, rowptr, inv, b2, Wsum, linb, out, n);
}

// Round 3
// 377.944 us; speedup vs baseline: 6.1242x; 1.3084x over previous
//
#include <hip/hip_runtime.h>

// GCN forward, CSR-gather, bf16 pre-scaled message buffers.
// x1 == x2 (dropout identity) => single branch, summed lin_W halves.
// h1s[i] = inv[i] * (x @ W1)[i]        (bf16)
// agg1[i] = relu( inv[i]*(sum_{s in N(i)} h1s[s] + h1s[i]) + b1 )   (fp32)
// h2s[i] = inv[i] * (agg1 @ W2)[i]     (bf16)
// z[i]   = inv[i]*(sum h2s[s] + h2s[i]) + b2
// out    = log_softmax(z @ (linW_top+linW_bot) + linb)

#define CIN  128
#define CHID 128
#define COUT 64
#define SB   256   // scan block size

static __device__ __forceinline__ unsigned short f2bf(float f) {
    unsigned int u = __float_as_uint(f);
    unsigned int r = (u + 0x7fffu + ((u >> 16) & 1u)) >> 16;  // RNE
    return (unsigned short)r;
}
static __device__ __forceinline__ float bf2f(unsigned short v) {
    return __uint_as_float(((unsigned int)v) << 16);
}

// ---------------- degree ----------------
__global__ void deg_count_kernel(const int* __restrict__ dst, int* __restrict__ cnt, int E) {
    int e = blockIdx.x * blockDim.x + threadIdx.x;
    if (e < E) atomicAdd(&cnt[dst[e]], 1);
}

// ---------------- hierarchical scan: pass 1, per-block sums ----------------
__global__ __launch_bounds__(SB) void bsum_kernel(const int* __restrict__ cnt,
                                                  int* __restrict__ bsum, int n) {
    __shared__ int s[SB];
    int t = threadIdx.x, g = blockIdx.x * SB + t;
    s[t] = (g < n) ? cnt[g] : 0;
    __syncthreads();
    for (int off = SB / 2; off >= 1; off >>= 1) {
        if (t < off) s[t] += s[t + off];
        __syncthreads();
    }
    if (t == 0) bsum[blockIdx.x] = s[0];
}

// ---------------- pass 2: 1-block exclusive scan of block sums ----------------
__global__ __launch_bounds__(SB) void bscan_kernel(int* __restrict__ bsum, int nb) {
    __shared__ int s[SB];
    int t = threadIdx.x;
    int v = (t < nb) ? bsum[t] : 0;
    s[t] = v;
    __syncthreads();
    for (int off = 1; off < SB; off <<= 1) {
        int u = (t >= off) ? s[t - off] : 0;
        __syncthreads();
        s[t] += u;
        __syncthreads();
    }
    if (t < nb) bsum[t] = s[t] - v;  // exclusive
}

// ---------------- pass 3: per-block rescan + scatter rowptr/cursor, fused inv ----------------
__global__ __launch_bounds__(SB) void scan_scatter_kernel(const int* __restrict__ cnt,
                                                          const int* __restrict__ bsum,
                                                          int* __restrict__ rowptr,
                                                          int* __restrict__ cursor,
                                                          float* __restrict__ inv,
                                                          int n, int E) {
    __shared__ int s[SB];
    int t = threadIdx.x, g = blockIdx.x * SB + t;
    int c = (g < n) ? cnt[g] : 0;
    s[t] = c;
    __syncthreads();
    for (int off = 1; off < SB; off <<= 1) {
        int u = (t >= off) ? s[t - off] : 0;
        __syncthreads();
        s[t] += u;
        __syncthreads();
    }
    if (g < n) {
        int ex = bsum[blockIdx.x] + s[t] - c;
        rowptr[g] = ex;
        cursor[g] = ex;
        inv[g] = rsqrtf((float)(c + 1));  // +1: self-loop
    }
    if (g == 0) rowptr[n] = E;
}

// ---------------- bucket-fill ----------------
__global__ void fill_kernel(const int* __restrict__ src, const int* __restrict__ dst,
                            int* __restrict__ cursor, int* __restrict__ ebuf, int E) {
    int e = blockIdx.x * blockDim.x + threadIdx.x;
    if (e >= E) return;
    int pos = atomicAdd(&cursor[dst[e]], 1);
    ebuf[pos] = src[e];
}

// ---------------- GEMM: H[i] = inv[i] * (X @ W)[i], bf16 output ----------------
template <int K, int NOUT, int R>
__global__ void gemm_rows_bf16(const float* __restrict__ X, const float* __restrict__ W,
                               const float* __restrict__ inv, unsigned short* __restrict__ H,
                               int n) {
    __shared__ float xs[R][K];
    int j = threadIdx.x;
    int n0 = blockIdx.x * R;
#pragma unroll
    for (int r = 0; r < R; ++r)
        for (int k = j; k < K; k += NOUT)
            xs[r][k] = (n0 + r < n) ? X[(size_t)(n0 + r) * K + k] : 0.f;
    __syncthreads();
    float acc[R];
#pragma unroll
    for (int r = 0; r < R; ++r) acc[r] = 0.f;
#pragma unroll 4
    for (int k = 0; k < K; ++k) {
        float wv = W[k * NOUT + j];
#pragma unroll
        for (int r = 0; r < R; ++r) acc[r] = fmaf(xs[r][k], wv, acc[r]);
    }
#pragma unroll
    for (int r = 0; r < R; ++r)
        if (n0 + r < n) H[(size_t)(n0 + r) * NOUT + j] = f2bf(acc[r] * inv[n0 + r]);
}

// ---------------- layer-1 aggregate (C=128 bf16): wave/node, uint(=2bf16)/lane ----
__global__ void agg1_kernel(const unsigned int* __restrict__ Hs, const int* __restrict__ ebuf,
                            const int* __restrict__ rowptr, const float* __restrict__ inv,
                            const float* __restrict__ bias, float* __restrict__ outp, int n) {
    int node = blockIdx.x * 4 + (threadIdx.x >> 6);
    int lane = threadIdx.x & 63;
    if (node >= n) return;
    int beg = rowptr[node], end = rowptr[node + 1];
    float ax = 0.f, ay = 0.f;
    for (int base = beg; base < end; base += 64) {
        int m = end - base; if (m > 64) m = 64;
        int sid = (lane < m) ? ebuf[base + lane] : 0;
        for (int k = 0; k < m; ++k) {
            int s = __shfl(sid, k, 64);
            unsigned int u = Hs[(size_t)s * 64 + lane];
            ax += __uint_as_float(u << 16);
            ay += __uint_as_float(u & 0xffff0000u);
        }
    }
    {   // self-loop term
        unsigned int u = Hs[(size_t)node * 64 + lane];
        ax += __uint_as_float(u << 16);
        ay += __uint_as_float(u & 0xffff0000u);
    }
    float wd = inv[node];
    float2 bv = ((const float2*)bias)[lane];
    float ox = fmaxf(fmaf(wd, ax, bv.x), 0.f);
    float oy = fmaxf(fmaf(wd, ay, bv.y), 0.f);
    ((float2*)outp)[(size_t)node * 64 + lane] = make_float2(ox, oy);
}

// ---------------- Wsum = linW[0:64,:] + linW[64:128,:] ----------------
__global__ void wsum_kernel(const float* __restrict__ linW, float* __restrict__ Wsum) {
    int i = blockIdx.x * blockDim.x + threadIdx.x;
    if (i < COUT * COUT) Wsum[i] = linW[i] + linW[COUT * COUT + i];
}

// ---------------- layer-2 aggregate + fused concat-linear + log_softmax --------
__global__ void agg2_final_kernel(const unsigned short* __restrict__ Hs,
                                  const int* __restrict__ ebuf, const int* __restrict__ rowptr,
                                  const float* __restrict__ inv, const float* __restrict__ bias,
                                  const float* __restrict__ Wsum, const float* __restrict__ linb,
                                  float* __restrict__ outp, int n) {
    int node = blockIdx.x * 4 + (threadIdx.x >> 6);
    int lane = threadIdx.x & 63;
    if (node >= n) return;
    int beg = rowptr[node], end = rowptr[node + 1];
    float acc = 0.f;
    for (int base = beg; base < end; base += 64) {
        int m = end - base; if (m > 64) m = 64;
        int sid = (lane < m) ? ebuf[base + lane] : 0;
        for (int k = 0; k < m; ++k) {
            int s = __shfl(sid, k, 64);
            acc += bf2f(Hs[(size_t)s * 64 + lane]);
        }
    }
    acc += bf2f(Hs[(size_t)node * 64 + lane]);  // self-loop
    float z = fmaf(inv[node], acc, bias[lane]);
    // fused concat-linear
    float fo = linb[lane];
#pragma unroll 8
    for (int k = 0; k < COUT; ++k) {
        float zk = __shfl(z, k, 64);
        fo = fmaf(zk, Wsum[k * COUT + lane], fo);
    }
    // log_softmax across the wave
    float mx = fo;
#pragma unroll
    for (int off = 32; off >= 1; off >>= 1) mx = fmaxf(mx, __shfl_xor(mx, off, 64));
    float ex = expf(fo - mx);
    float s = ex;
#pragma unroll
    for (int off = 32; off >= 1; off >>= 1) s += __shfl_xor(s, off, 64);
    outp[(size_t)node * COUT + lane] = fo - mx - logf(s);
}

static inline size_t align16(size_t x) { return (x + 15) & ~(size_t)15; }

extern "C" void kernel_launch(void* const* d_in, const int* in_sizes, int n_in,
                              void* d_out, int out_size, void* d_ws, size_t ws_size,
                              hipStream_t stream) {
    const float* x    = (const float*)d_in[0];
    const int*   eidx = (const int*)d_in[1];
    const float* W1   = (const float*)d_in[2];
    const float* b1   = (const float*)d_in[3];
    const float* W2   = (const float*)d_in[4];
    const float* b2   = (const float*)d_in[5];
    const float* linW = (const float*)d_in[6];
    const float* linb = (const float*)d_in[7];
    float* out = (float*)d_out;

    const int n = in_sizes[0] / CIN;   // 50000
    const int E = in_sizes[1] / 2;     // 800000
    const int* src = eidx;
    const int* dst = eidx + E;
    const int NB = (n + SB - 1) / SB;  // scan blocks (196)

    // ---- workspace carve-up
    char* ws = (char*)d_ws;
    size_t off = 0;
    int*   cnt    = (int*)(ws + off);   off = align16(off + (size_t)n * 4);
    int*   rowptr = (int*)(ws + off);   off = align16(off + (size_t)(n + 1) * 4);
    int*   cursor = (int*)(ws + off);   off = align16(off + (size_t)n * 4);
    float* inv    = (float*)(ws + off); off = align16(off + (size_t)n * 4);
    int*   bsum   = (int*)(ws + off);   off = align16(off + (size_t)SB * 4);
    float* Wsum   = (float*)(ws + off); off = align16(off + (size_t)COUT * COUT * 4);
    int*   ebuf   = (int*)(ws + off);   off = align16(off + (size_t)E * 4);
    unsigned short* h1s = (unsigned short*)(ws + off); off = align16(off + (size_t)n * CHID * 2);
    float* agg1   = (float*)(ws + off); off = align16(off + (size_t)n * CHID * 4);
    unsigned short* h2s = (unsigned short*)(ws + off); off = align16(off + (size_t)n * COUT * 2);

    hipMemsetAsync(cnt, 0, (size_t)n * 4, stream);

    // ---- CSR build (hierarchical scan)
    deg_count_kernel<<<(E + 255) / 256, 256, 0, stream>>>(dst, cnt, E);
    bsum_kernel<<<NB, SB, 0, stream>>>(cnt, bsum, n);
    bscan_kernel<<<1, SB, 0, stream>>>(bsum, NB);
    scan_scatter_kernel<<<NB, SB, 0, stream>>>(cnt, bsum, rowptr, cursor, inv, n, E);
    fill_kernel<<<(E + 255) / 256, 256, 0, stream>>>(src, dst, cursor, ebuf, E);
    wsum_kernel<<<(COUT * COUT + 255) / 256, 256, 0, stream>>>(linW, Wsum);

    // ---- layer 1
    gemm_rows_bf16<CIN, CHID, 4><<<(n + 3) / 4, CHID, 0, stream>>>(x, W1, inv, h1s, n);
    agg1_kernel<<<(n + 3) / 4, 256, 0, stream>>>((const unsigned int*)h1s, ebuf, rowptr, inv, b1, agg1, n);

    // ---- layer 2 + fused final
    gemm_rows_bf16<CHID, COUT, 8><<<(n + 7) / 8, COUT, 0, stream>>>(agg1, W2, inv, h2s, n);
    agg2_final_kernel<<<(n + 3) / 4, 256, 0, stream>>>(h2s, ebuf, rowptr, inv, b2, Wsum, linb, out, n);
}

// Round 4
// 321.691 us; speedup vs baseline: 7.1951x; 1.1749x over previous
//
#include <hip/hip_runtime.h>

// GCN forward, CSR-gather, bf16 pre-scaled message buffers, scalar edge walk.
// x1 == x2 (dropout identity) => single branch, summed lin_W halves.
// h1s[i] = inv[i] * (x @ W1)[i]        (bf16)
// agg1[i] = relu( inv[i]*(sum_{s in N(i)} h1s[s] + h1s[i]) + b1 )   (fp32)
// h2s[i] = inv[i] * (agg1 @ W2)[i]     (bf16)
// z[i]   = inv[i]*(sum h2s[s] + h2s[i]) + b2
// out    = log_softmax(z @ (linW_top+linW_bot) + linb)

#define CIN  128
#define CHID 128
#define COUT 64
#define SB   256   // scan block size

static __device__ __forceinline__ unsigned short f2bf(float f) {
    unsigned int u = __float_as_uint(f);
    unsigned int r = (u + 0x7fffu + ((u >> 16) & 1u)) >> 16;  // RNE
    return (unsigned short)r;
}
static __device__ __forceinline__ float bf2f(unsigned short v) {
    return __uint_as_float(((unsigned int)v) << 16);
}

// ---------------- degree ----------------
__global__ void deg_count_kernel(const int* __restrict__ dst, int* __restrict__ cnt, int E) {
    int e = blockIdx.x * blockDim.x + threadIdx.x;
    if (e < E) atomicAdd(&cnt[dst[e]], 1);
}

// ---------------- hierarchical scan: pass 1, per-block sums ----------------
__global__ __launch_bounds__(SB) void bsum_kernel(const int* __restrict__ cnt,
                                                  int* __restrict__ bsum, int n) {
    __shared__ int s[SB];
    int t = threadIdx.x, g = blockIdx.x * SB + t;
    s[t] = (g < n) ? cnt[g] : 0;
    __syncthreads();
    for (int off = SB / 2; off >= 1; off >>= 1) {
        if (t < off) s[t] += s[t + off];
        __syncthreads();
    }
    if (t == 0) bsum[blockIdx.x] = s[0];
}

// ---------------- pass 2: 1-block exclusive scan of block sums ----------------
__global__ __launch_bounds__(SB) void bscan_kernel(int* __restrict__ bsum, int nb) {
    __shared__ int s[SB];
    int t = threadIdx.x;
    int v = (t < nb) ? bsum[t] : 0;
    s[t] = v;
    __syncthreads();
    for (int off = 1; off < SB; off <<= 1) {
        int u = (t >= off) ? s[t - off] : 0;
        __syncthreads();
        s[t] += u;
        __syncthreads();
    }
    if (t < nb) bsum[t] = s[t] - v;  // exclusive
}

// ---------------- pass 3: per-block rescan + scatter rowptr/cursor, fused inv ----------------
__global__ __launch_bounds__(SB) void scan_scatter_kernel(const int* __restrict__ cnt,
                                                          const int* __restrict__ bsum,
                                                          int* __restrict__ rowptr,
                                                          int* __restrict__ cursor,
                                                          float* __restrict__ inv,
                                                          int n, int E) {
    __shared__ int s[SB];
    int t = threadIdx.x, g = blockIdx.x * SB + t;
    int c = (g < n) ? cnt[g] : 0;
    s[t] = c;
    __syncthreads();
    for (int off = 1; off < SB; off <<= 1) {
        int u = (t >= off) ? s[t - off] : 0;
        __syncthreads();
        s[t] += u;
        __syncthreads();
    }
    if (g < n) {
        int ex = bsum[blockIdx.x] + s[t] - c;
        rowptr[g] = ex;
        cursor[g] = ex;
        inv[g] = rsqrtf((float)(c + 1));  // +1: self-loop
    }
    if (g == 0) rowptr[n] = E;
}

// ---------------- bucket-fill ----------------
__global__ void fill_kernel(const int* __restrict__ src, const int* __restrict__ dst,
                            int* __restrict__ cursor, int* __restrict__ ebuf, int E) {
    int e = blockIdx.x * blockDim.x + threadIdx.x;
    if (e >= E) return;
    int pos = atomicAdd(&cursor[dst[e]], 1);
    ebuf[pos] = src[e];
}

// ---------------- GEMM: H[i] = inv[i] * (X @ W)[i], bf16 output ----------------
// NOUT threads, R rows/block; LDS reads are b128 wave-uniform broadcasts.
template <int K, int NOUT, int R>
__global__ void gemm_rows_bf16(const float* __restrict__ X, const float* __restrict__ W,
                               const float* __restrict__ inv, unsigned short* __restrict__ H,
                               int n) {
    __shared__ float xs[R][K];
    int j = threadIdx.x;
    int n0 = blockIdx.x * R;
    // float4 staging
    constexpr int NF4 = R * K / 4;
    const float4* X4 = (const float4*)(X + (size_t)n0 * K);
    for (int t = j; t < NF4; t += NOUT) {
        int r = t / (K / 4);
        float4 v = (n0 + r < n) ? X4[t] : make_float4(0.f, 0.f, 0.f, 0.f);
        ((float4*)xs)[t] = v;
    }
    __syncthreads();
    float acc[R];
#pragma unroll
    for (int r = 0; r < R; ++r) acc[r] = 0.f;
    for (int k4 = 0; k4 < K / 4; ++k4) {
        float4 xv[R];
#pragma unroll
        for (int r = 0; r < R; ++r) xv[r] = ((const float4*)xs[r])[k4];
        float w0 = W[(k4 * 4 + 0) * NOUT + j];
        float w1 = W[(k4 * 4 + 1) * NOUT + j];
        float w2 = W[(k4 * 4 + 2) * NOUT + j];
        float w3 = W[(k4 * 4 + 3) * NOUT + j];
#pragma unroll
        for (int r = 0; r < R; ++r) {
            acc[r] = fmaf(xv[r].x, w0, acc[r]);
            acc[r] = fmaf(xv[r].y, w1, acc[r]);
            acc[r] = fmaf(xv[r].z, w2, acc[r]);
            acc[r] = fmaf(xv[r].w, w3, acc[r]);
        }
    }
#pragma unroll
    for (int r = 0; r < R; ++r)
        if (n0 + r < n) H[(size_t)(n0 + r) * NOUT + j] = f2bf(acc[r] * inv[n0 + r]);
}

// ---------------- layer-1 aggregate (C=128 bf16): wave/node, scalar edge walk ----
__global__ void agg1_kernel(const unsigned int* __restrict__ Hs, const int* __restrict__ ebuf,
                            const int* __restrict__ rowptr, const float* __restrict__ inv,
                            const float* __restrict__ bias, float* __restrict__ outp, int n) {
    int node = __builtin_amdgcn_readfirstlane(blockIdx.x * 4 + (threadIdx.x >> 6));
    int lane = threadIdx.x & 63;
    if (node >= n) return;
    int beg = rowptr[node], end = rowptr[node + 1];  // uniform addr -> s_load
    float ax = 0.f, ay = 0.f;
#pragma unroll 4
    for (int k = beg; k < end; ++k) {
        int s = ebuf[k];                             // uniform addr -> s_load
        unsigned int u = Hs[(size_t)s * 64 + lane];  // sgpr base + lane offset
        ax += __uint_as_float(u << 16);
        ay += __uint_as_float(u & 0xffff0000u);
    }
    {   // self-loop term
        unsigned int u = Hs[(size_t)node * 64 + lane];
        ax += __uint_as_float(u << 16);
        ay += __uint_as_float(u & 0xffff0000u);
    }
    float wd = inv[node];
    float2 bv = ((const float2*)bias)[lane];
    float ox = fmaxf(fmaf(wd, ax, bv.x), 0.f);
    float oy = fmaxf(fmaf(wd, ay, bv.y), 0.f);
    ((float2*)outp)[(size_t)node * 64 + lane] = make_float2(ox, oy);
}

// ---------------- Wsum = linW[0:64,:] + linW[64:128,:] ----------------
__global__ void wsum_kernel(const float* __restrict__ linW, float* __restrict__ Wsum) {
    int i = blockIdx.x * blockDim.x + threadIdx.x;
    if (i < COUT * COUT) Wsum[i] = linW[i] + linW[COUT * COUT + i];
}

// ---------------- layer-2 aggregate + fused concat-linear + log_softmax --------
__global__ void agg2_final_kernel(const unsigned short* __restrict__ Hs,
                                  const int* __restrict__ ebuf, const int* __restrict__ rowptr,
                                  const float* __restrict__ inv, const float* __restrict__ bias,
                                  const float* __restrict__ Wsum, const float* __restrict__ linb,
                                  float* __restrict__ outp, int n) {
    int node = __builtin_amdgcn_readfirstlane(blockIdx.x * 4 + (threadIdx.x >> 6));
    int lane = threadIdx.x & 63;
    if (node >= n) return;
    int beg = rowptr[node], end = rowptr[node + 1];  // uniform -> s_load
    float acc = 0.f;
#pragma unroll 4
    for (int k = beg; k < end; ++k) {
        int s = ebuf[k];                             // uniform -> s_load
        acc += bf2f(Hs[(size_t)s * 64 + lane]);
    }
    acc += bf2f(Hs[(size_t)node * 64 + lane]);       // self-loop
    float z = fmaf(inv[node], acc, bias[lane]);
    // fused concat-linear
    float fo = linb[lane];
#pragma unroll 8
    for (int k = 0; k < COUT; ++k) {
        float zk = __shfl(z, k, 64);
        fo = fmaf(zk, Wsum[k * COUT + lane], fo);
    }
    // log_softmax across the wave
    float mx = fo;
#pragma unroll
    for (int off = 32; off >= 1; off >>= 1) mx = fmaxf(mx, __shfl_xor(mx, off, 64));
    float ex = expf(fo - mx);
    float s = ex;
#pragma unroll
    for (int off = 32; off >= 1; off >>= 1) s += __shfl_xor(s, off, 64);
    outp[(size_t)node * COUT + lane] = fo - mx - logf(s);
}

static inline size_t align16(size_t x) { return (x + 15) & ~(size_t)15; }

extern "C" void kernel_launch(void* const* d_in, const int* in_sizes, int n_in,
                              void* d_out, int out_size, void* d_ws, size_t ws_size,
                              hipStream_t stream) {
    const float* x    = (const float*)d_in[0];
    const int*   eidx = (const int*)d_in[1];
    const float* W1   = (const float*)d_in[2];
    const float* b1   = (const float*)d_in[3];
    const float* W2   = (const float*)d_in[4];
    const float* b2   = (const float*)d_in[5];
    const float* linW = (const float*)d_in[6];
    const float* linb = (const float*)d_in[7];
    float* out = (float*)d_out;

    const int n = in_sizes[0] / CIN;   // 50000
    const int E = in_sizes[1] / 2;     // 800000
    const int* src = eidx;
    const int* dst = eidx + E;
    const int NB = (n + SB - 1) / SB;

    // ---- workspace carve-up
    char* ws = (char*)d_ws;
    size_t off = 0;
    int*   cnt    = (int*)(ws + off);   off = align16(off + (size_t)n * 4);
    int*   rowptr = (int*)(ws + off);   off = align16(off + (size_t)(n + 1) * 4);
    int*   cursor = (int*)(ws + off);   off = align16(off + (size_t)n * 4);
    float* inv    = (float*)(ws + off); off = align16(off + (size_t)n * 4);
    int*   bsum   = (int*)(ws + off);   off = align16(off + (size_t)SB * 4);
    float* Wsum   = (float*)(ws + off); off = align16(off + (size_t)COUT * COUT * 4);
    int*   ebuf   = (int*)(ws + off);   off = align16(off + (size_t)E * 4);
    unsigned short* h1s = (unsigned short*)(ws + off); off = align16(off + (size_t)n * CHID * 2);
    float* agg1   = (float*)(ws + off); off = align16(off + (size_t)n * CHID * 4);
    unsigned short* h2s = (unsigned short*)(ws + off); off = align16(off + (size_t)n * COUT * 2);

    hipMemsetAsync(cnt, 0, (size_t)n * 4, stream);

    // ---- CSR build (hierarchical scan)
    deg_count_kernel<<<(E + 255) / 256, 256, 0, stream>>>(dst, cnt, E);
    bsum_kernel<<<NB, SB, 0, stream>>>(cnt, bsum, n);
    bscan_kernel<<<1, SB, 0, stream>>>(bsum, NB);
    scan_scatter_kernel<<<NB, SB, 0, stream>>>(cnt, bsum, rowptr, cursor, inv, n, E);
    fill_kernel<<<(E + 255) / 256, 256, 0, stream>>>(src, dst, cursor, ebuf, E);
    wsum_kernel<<<(COUT * COUT + 255) / 256, 256, 0, stream>>>(linW, Wsum);

    // ---- layer 1
    gemm_rows_bf16<CIN, CHID, 8><<<(n + 7) / 8, CHID, 0, stream>>>(x, W1, inv, h1s, n);
    agg1_kernel<<<(n + 3) / 4, 256, 0, stream>>>((const unsigned int*)h1s, ebuf, rowptr, inv, b1, agg1, n);

    // ---- layer 2 + fused final
    gemm_rows_bf16<CHID, COUT, 16><<<(n + 15) / 16, COUT, 0, stream>>>(agg1, W2, inv, h2s, n);
    agg2_final_kernel<<<(n + 3) / 4, 256, 0, stream>>>(h2s, ebuf, rowptr, inv, b2, Wsum, linb, out, n);
}